// Round 7
// baseline (167.467 us; speedup 1.0000x reference)
//
#include <hip/hip_runtime.h>
#include <cstdint>
#include <cstddef>

#define SEQ   2048
#define HID   2048
#define NHEAD 16
#define HDIM  128
#define NQKV  2560
#define KOFF  2048
#define VOFF  2304
#define SCALE 0.08838834764831845f

typedef __bf16 bf16_t;
typedef __attribute__((ext_vector_type(8))) __bf16 bf16x8;
typedef __attribute__((ext_vector_type(4))) float f32x4;

static __device__ __forceinline__ void gl_lds16(const void* g, void* l) {
  __builtin_amdgcn_global_load_lds((const __attribute__((address_space(1))) void*)g,
                                   (__attribute__((address_space(3))) void*)l, 16, 0, 0);
}

// ---------- fused prep: x->bf16, W transposes (64x64 tiles), bias concat ----------
// blocks: [0,2048) cvt ; [2048,3072) Wq ; [3072,3200) Wk ; [3200,3328) Wv ;
// [3328,4352) Wo ; [4352,4362) bias.
__global__ __launch_bounds__(256) void k_prep(const float* __restrict__ x,
                                              const float* __restrict__ Wq,
                                              const float* __restrict__ Wk,
                                              const float* __restrict__ Wv,
                                              const float* __restrict__ Wo,
                                              const float* __restrict__ bq,
                                              const float* __restrict__ bk,
                                              const float* __restrict__ bv,
                                              bf16_t* __restrict__ xb,
                                              bf16_t* __restrict__ WqkvT,
                                              bf16_t* __restrict__ WoT,
                                              float* __restrict__ bias) {
  __shared__ float t[64][65];
  int b = blockIdx.x;
  const int tid = threadIdx.x;
  if (b < 2048) {  // x convert, 8 floats/thread
    int i = b * 256 + tid;
    const float4* p = (const float4*)x;
    float4 a = p[2 * i], c = p[2 * i + 1];
    bf16x8 o;
    o[0] = (bf16_t)a.x; o[1] = (bf16_t)a.y; o[2] = (bf16_t)a.z; o[3] = (bf16_t)a.w;
    o[4] = (bf16_t)c.x; o[5] = (bf16_t)c.y; o[6] = (bf16_t)c.z; o[7] = (bf16_t)c.w;
    ((bf16x8*)xb)[i] = o;
    return;
  }
  b -= 2048;
  const float* src;
  bf16_t* dst;
  int N, bx, by;
  if (b < 1024) {
    src = Wq; dst = WqkvT; N = 2048; bx = b & 31; by = b >> 5;
  } else if (b < 1152) {
    int tb = b - 1024; src = Wk; dst = WqkvT + (size_t)2048 * 2048; N = 256; bx = tb & 3; by = tb >> 2;
  } else if (b < 1280) {
    int tb = b - 1152; src = Wv; dst = WqkvT + (size_t)2304 * 2048; N = 256; bx = tb & 3; by = tb >> 2;
  } else if (b < 2304) {
    int tb = b - 1280; src = Wo; dst = WoT; N = 2048; bx = tb & 31; by = tb >> 5;
  } else {
    int i = (b - 2304) * 256 + tid;
    if (i < NQKV) bias[i] = (i < KOFF) ? bq[i] : ((i < VOFF) ? bk[i - KOFF] : bv[i - VOFF]);
    return;
  }
  // 64x64 transpose tile: fp32 [K=2048][N] -> bf16 [N][2048]
  int xq = tid & 63, yq = tid >> 6;
  int c0 = bx * 64, r0 = by * 64;
#pragma unroll
  for (int j = 0; j < 64; j += 4) t[yq + j][xq] = src[(size_t)(r0 + yq + j) * N + c0 + xq];
  __syncthreads();
#pragma unroll
  for (int j = 0; j < 64; j += 4)
    dst[(size_t)(c0 + yq + j) * 2048 + r0 + xq] = (bf16_t)t[xq][yq + j];
}

// ---------- fused projection GEMM (grid = 256 exactly, no tail) ----------
// bid<192 : QK  : C[0:2048,0:2304) = xb @ WqkvT^T + bias  (BM=128,BN=192,BK=32)
// bid>=192: V^T : Vg[d][sigma(s)] = WvT @ xb^T + bv       (BM=128,BN=64, BK=32)
// Both: triple-buffered LDS, 2-deep prefetch, counted vmcnt, raw s_barrier,
// LDS swizzle ss = sp ^ ((r>>3)&3).
__global__ __launch_bounds__(256) void k_proj(const bf16_t* __restrict__ xb,
                                              const bf16_t* __restrict__ WqkvT,
                                              const float* __restrict__ bias,
                                              bf16_t* __restrict__ QKV,
                                              bf16_t* __restrict__ Vg) {
  __shared__ __align__(16) char smem[61440];
  const int tid = threadIdx.x;
  const int l = tid & 63, w = tid >> 6;
  const int lr = l & 15, lg = l >> 4;
  const int bid = blockIdx.x;
  const int K = 2048, NT = 64;

  if (bid < 192) {
    bf16_t* As = (bf16_t*)smem;            // [3][128*32]
    bf16_t* Bs = (bf16_t*)(smem + 24576);  // [3][192*32]
    const int b = (bid & 7) * 24 + (bid >> 3);  // XCD swizzle (192 = 8*24)
    const int m0 = (b / 12) * 128, n0 = (b % 12) * 192;
    const int wm = (w >> 1) * 64, wn = (w & 1) * 96;
    f32x4 acc[4][6] = {};

#define QSTAGE(buf, ktv)                                                         \
  {                                                                              \
    _Pragma("unroll") for (int t = 0; t < 2; ++t) {                              \
      int c = t * 256 + tid;                                                     \
      int r = c >> 2, ss = (c & 3) ^ ((r >> 3) & 3);                             \
      gl_lds16(xb + (size_t)(m0 + r) * K + (ktv) + ss * 8,                       \
               As + (size_t)(buf) * 4096 + (size_t)(t * 256 + w * 64) * 8);      \
    }                                                                            \
    _Pragma("unroll") for (int t = 0; t < 3; ++t) {                              \
      int c = t * 256 + tid;                                                     \
      int r = c >> 2, ss = (c & 3) ^ ((r >> 3) & 3);                             \
      gl_lds16(WqkvT + (size_t)(n0 + r) * K + (ktv) + ss * 8,                    \
               Bs + (size_t)(buf) * 6144 + (size_t)(t * 256 + w * 64) * 8);      \
    }                                                                            \
  }
    QSTAGE(0, 0);
    QSTAGE(1, 32);
    int bufc = 0;
    for (int i = 0; i < NT; ++i) {
      if (i + 2 < NT) {
        int bn = bufc + 2; if (bn >= 3) bn -= 3;
        QSTAGE(bn, (i + 2) * 32);
        asm volatile("s_waitcnt vmcnt(10)" ::: "memory");
      } else if (i + 2 == NT) {
        asm volatile("s_waitcnt vmcnt(5)" ::: "memory");
      } else {
        asm volatile("s_waitcnt vmcnt(0)" ::: "memory");
      }
      asm volatile("s_barrier" ::: "memory");
      bf16x8 af[4], bfr[6];
#pragma unroll
      for (int i4 = 0; i4 < 4; ++i4) {
        int ra = wm + i4 * 16 + lr;
        af[i4] = *(const bf16x8*)(As + (size_t)bufc * 4096 + ra * 32 + (lg ^ ((ra >> 3) & 3)) * 8);
      }
#pragma unroll
      for (int i4 = 0; i4 < 6; ++i4) {
        int rb = wn + i4 * 16 + lr;
        bfr[i4] = *(const bf16x8*)(Bs + (size_t)bufc * 6144 + rb * 32 + (lg ^ ((rb >> 3) & 3)) * 8);
      }
#pragma unroll
      for (int mi = 0; mi < 4; ++mi)
#pragma unroll
        for (int ni = 0; ni < 6; ++ni)
          acc[mi][ni] =
              __builtin_amdgcn_mfma_f32_16x16x32_bf16(af[mi], bfr[ni], acc[mi][ni], 0, 0, 0);
      asm volatile("s_barrier" ::: "memory");
      bufc = (bufc + 1 == 3) ? 0 : bufc + 1;
    }
#undef QSTAGE
#pragma unroll
    for (int mi = 0; mi < 4; ++mi)
#pragma unroll
      for (int ni = 0; ni < 6; ++ni) {
        int col = n0 + wn + ni * 16 + lr;
        float bb = bias[col];
#pragma unroll
        for (int r = 0; r < 4; ++r) {
          int row = m0 + wm + mi * 16 + lg * 4 + r;
          QKV[(size_t)row * NQKV + col] = (bf16_t)(acc[mi][ni][r] + bb);
        }
      }
  } else {
    bf16_t* As = (bf16_t*)smem;            // [3][128*32]  (WvT tiles)
    bf16_t* Bs = (bf16_t*)(smem + 24576);  // [3][64*32]   (xb tiles)
    const bf16_t* WvT = WqkvT + (size_t)VOFF * 2048;
    const int b2 = bid - 192;
    const int m0 = (b2 >> 5) * 128, n0 = (b2 & 31) * 64;
    const int wm = (w >> 1) * 64, wn = (w & 1) * 32;
    f32x4 acc[4][2] = {};

#define VSTAGE(buf, ktv)                                                         \
  {                                                                              \
    _Pragma("unroll") for (int t = 0; t < 2; ++t) {                              \
      int c = t * 256 + tid;                                                     \
      int r = c >> 2, ss = (c & 3) ^ ((r >> 3) & 3);                             \
      gl_lds16(WvT + (size_t)(m0 + r) * K + (ktv) + ss * 8,                      \
               As + (size_t)(buf) * 4096 + (size_t)(t * 256 + w * 64) * 8);      \
    }                                                                            \
    {                                                                            \
      int c = tid;                                                               \
      int r = c >> 2, ss = (c & 3) ^ ((r >> 3) & 3);                             \
      gl_lds16(xb + (size_t)(n0 + r) * K + (ktv) + ss * 8,                       \
               Bs + (size_t)(buf) * 2048 + (size_t)(w * 64) * 8);                \
    }                                                                            \
  }
    VSTAGE(0, 0);
    VSTAGE(1, 32);
    int bufc = 0;
    for (int i = 0; i < NT; ++i) {
      if (i + 2 < NT) {
        int bn = bufc + 2; if (bn >= 3) bn -= 3;
        VSTAGE(bn, (i + 2) * 32);
        asm volatile("s_waitcnt vmcnt(6)" ::: "memory");
      } else if (i + 2 == NT) {
        asm volatile("s_waitcnt vmcnt(3)" ::: "memory");
      } else {
        asm volatile("s_waitcnt vmcnt(0)" ::: "memory");
      }
      asm volatile("s_barrier" ::: "memory");
      bf16x8 af[4], bfr[2];
#pragma unroll
      for (int i4 = 0; i4 < 4; ++i4) {
        int ra = wm + i4 * 16 + lr;
        af[i4] = *(const bf16x8*)(As + (size_t)bufc * 4096 + ra * 32 + (lg ^ ((ra >> 3) & 3)) * 8);
      }
#pragma unroll
      for (int i4 = 0; i4 < 2; ++i4) {
        int rb = wn + i4 * 16 + lr;
        bfr[i4] = *(const bf16x8*)(Bs + (size_t)bufc * 2048 + rb * 32 + (lg ^ ((rb >> 3) & 3)) * 8);
      }
#pragma unroll
      for (int mi = 0; mi < 4; ++mi)
#pragma unroll
        for (int ni = 0; ni < 2; ++ni)
          acc[mi][ni] =
              __builtin_amdgcn_mfma_f32_16x16x32_bf16(af[mi], bfr[ni], acc[mi][ni], 0, 0, 0);
      asm volatile("s_barrier" ::: "memory");
      bufc = (bufc + 1 == 3) ? 0 : bufc + 1;
    }
#undef VSTAGE
#pragma unroll
    for (int mi = 0; mi < 4; ++mi)
#pragma unroll
      for (int ni = 0; ni < 2; ++ni) {
        int s = n0 + wn + ni * 16 + lr;
        int sig = (s & ~31) | ((s & 15) << 1) | ((s >> 4) & 1);
#pragma unroll
        for (int r = 0; r < 4; ++r) {
          int d = m0 + wm + mi * 16 + lg * 4 + r;
          Vg[(size_t)d * SEQ + sig] = (bf16_t)(acc[mi][ni][r] + bias[VOFF + d]);
        }
      }
  }
}

// ---------- O-projection GEMM (unchanged, XCD swizzle, grid 256) ----------
template <int BIAS, typename OUTT>
__global__ __launch_bounds__(256) void k_gemm(const bf16_t* __restrict__ A,
                                              const bf16_t* __restrict__ Bt,
                                              const float* __restrict__ bias,
                                              OUTT* __restrict__ C,
                                              int M, int N, int K) {
  __shared__ __align__(16) bf16_t As[3][128 * 32];
  __shared__ __align__(16) bf16_t Bs[3][128 * 32];
  const int tid = threadIdx.x;
  const int l = tid & 63, w = tid >> 6;
  const int lr = l & 15, lg = l >> 4;
  const int nwg = gridDim.x * gridDim.y;
  const int bid = blockIdx.y * gridDim.x + blockIdx.x;
  const int swz = (bid & 7) * (nwg >> 3) + (bid >> 3);
  const int m0 = (swz / gridDim.x) * 128, n0 = (swz % gridDim.x) * 128;
  const int wm = (w >> 1) * 64, wn = (w & 1) * 64;
  const int NT = K >> 5;
  f32x4 acc[4][4] = {};

#define GSTAGE(buf, ktv)                                                          \
  {                                                                               \
    _Pragma("unroll") for (int t = 0; t < 2; ++t) {                               \
      int c = t * 256 + tid;                                                      \
      int r = c >> 2, ss = (c & 3) ^ ((r >> 3) & 3);                              \
      gl_lds16(A + (size_t)(m0 + r) * K + (ktv) + ss * 8,                         \
               &As[buf][(size_t)(t * 256 + w * 64) * 8]);                         \
    }                                                                             \
    _Pragma("unroll") for (int t = 0; t < 2; ++t) {                               \
      int c = t * 256 + tid;                                                      \
      int r = c >> 2, ss = (c & 3) ^ ((r >> 3) & 3);                              \
      gl_lds16(Bt + (size_t)(n0 + r) * K + (ktv) + ss * 8,                        \
               &Bs[buf][(size_t)(t * 256 + w * 64) * 8]);                         \
    }                                                                             \
  }

  GSTAGE(0, 0);
  GSTAGE(1, 32);
  int bufc = 0;
  for (int i = 0; i < NT; ++i) {
    if (i + 2 < NT) {
      int bn = bufc + 2; if (bn >= 3) bn -= 3;
      GSTAGE(bn, (i + 2) * 32);
      asm volatile("s_waitcnt vmcnt(8)" ::: "memory");
    } else if (i + 2 == NT) {
      asm volatile("s_waitcnt vmcnt(4)" ::: "memory");
    } else {
      asm volatile("s_waitcnt vmcnt(0)" ::: "memory");
    }
    asm volatile("s_barrier" ::: "memory");
    bf16x8 af[4], bfr[4];
#pragma unroll
    for (int i4 = 0; i4 < 4; ++i4) {
      int ra = wm + i4 * 16 + lr;
      af[i4] = *(const bf16x8*)&As[bufc][ra * 32 + (lg ^ ((ra >> 3) & 3)) * 8];
    }
#pragma unroll
    for (int i4 = 0; i4 < 4; ++i4) {
      int rb = wn + i4 * 16 + lr;
      bfr[i4] = *(const bf16x8*)&Bs[bufc][rb * 32 + (lg ^ ((rb >> 3) & 3)) * 8];
    }
#pragma unroll
    for (int mi = 0; mi < 4; ++mi)
#pragma unroll
      for (int ni = 0; ni < 4; ++ni)
        acc[mi][ni] =
            __builtin_amdgcn_mfma_f32_16x16x32_bf16(af[mi], bfr[ni], acc[mi][ni], 0, 0, 0);
    asm volatile("s_barrier" ::: "memory");
    bufc = (bufc + 1 == 3) ? 0 : bufc + 1;
  }
#undef GSTAGE

#pragma unroll
  for (int mi = 0; mi < 4; ++mi)
#pragma unroll
    for (int ni = 0; ni < 4; ++ni) {
      int col = n0 + wn + ni * 16 + lr;
      float bb = BIAS ? bias[col] : 0.0f;
#pragma unroll
      for (int r = 0; r < 4; ++r) {
        int row = m0 + wm + mi * 16 + lg * 4 + r;
        float v = acc[mi][ni][r] + bb;
        if constexpr (sizeof(OUTT) == 2)
          C[(size_t)row * N + col] = (OUTT)v;
        else
          C[(size_t)row * N + col] = v;
      }
    }
}

// ---------- flash attention, causal, GQA — swapped-QK^T, 32q/wave, k-split ----------
// grid (16 heads, 32 qblocks of 64); block 256 = 4 waves: qw=w&1 (q half), ks=w>>1
// (32-key half of each 64-key tile). Each wave: 32 q (2 subtiles of 16) x its 32 keys.
// K-frags read once, shared across both q-subtiles; V-frags shared too -> LDS reads
// per q halved vs R6. P stays in registers (swapped QK^T, verified layouts).
// Partial (m,l,O) per k-half; merged via LDS at block end. Layouts identical to R6.
__global__ __launch_bounds__(256) void k_attn(const bf16_t* __restrict__ QKV,
                                              const bf16_t* __restrict__ Vg,
                                              bf16_t* __restrict__ AO) {
  __shared__ __align__(16) bf16_t Kl[2 * 64 * 128];
  __shared__ __align__(16) bf16_t Vl[2 * 64 * 128];
  const int h = blockIdx.x;
  const int y = blockIdx.y;
  const int qb = (y < 16) ? (31 - y) : (y - 16);  // heavy+light pairing (sum const)
  const int hkv = h >> 3;
  const int tid = threadIdx.x;
  const int l = tid & 63, w = tid >> 6;
  const int lr = l & 15, lg = l >> 4;
  const int qw = w & 1, ks = w >> 1;
  const int q0 = qb * 64 + qw * 32;

  // Q fragments for both 16-row subtiles (B-operand: col=lane&15=q, k-slot=(lane>>4)*8)
  bf16x8 qf[2][4];
#pragma unroll
  for (int qh = 0; qh < 2; ++qh)
#pragma unroll
    for (int dt = 0; dt < 4; ++dt)
      qf[qh][dt] =
          *(const bf16x8*)(QKV + (size_t)(q0 + qh * 16 + lr) * NQKV + h * HDIM + dt * 32 + lg * 8);

  f32x4 oa[2][8] = {};
  float mm[2] = {-1e30f, -1e30f}, lsum[2] = {0.0f, 0.0f};

  // staging source pointers (pre-swizzled global source, linear LDS dest) — as R6
  const bf16_t* srcK[4];
  const bf16_t* srcV[4];
#pragma unroll
  for (int t = 0; t < 4; ++t) {
    int c = t * 256 + tid;
    int r = c >> 4, ss = (c & 15) ^ (r & 15);
    srcK[t] = QKV + (size_t)r * NQKV + KOFF + hkv * HDIM + ss * 8;
    srcV[t] = Vg + (size_t)(hkv * HDIM + 2 * r + (ss >> 3)) * SEQ + (ss & 7) * 8;
  }

#define STAGE(b, kbv)                                                        \
  {                                                                          \
    bf16_t* Kb = Kl + (b) * 8192;                                            \
    bf16_t* Vb = Vl + (b) * 8192;                                            \
    _Pragma("unroll") for (int t = 0; t < 4; ++t)                            \
        gl_lds16(srcK[t] + (size_t)(kbv) * 64 * NQKV,                        \
                 Kb + (size_t)(t * 256 + w * 64) * 8);                       \
    _Pragma("unroll") for (int t = 0; t < 4; ++t)                            \
        gl_lds16(srcV[t] + (kbv) * 64, Vb + (size_t)(t * 256 + w * 64) * 8); \
  }

  STAGE(0, 0);
  asm volatile("s_waitcnt vmcnt(0)" ::: "memory");
  __syncthreads();
  int cur = 0;

  for (int kb = 0; kb <= qb; ++kb) {
    if (kb < qb) STAGE(cur ^ 1, kb + 1);
    const bf16_t* Kb = Kl + cur * 8192;
    const bf16_t* Vb = Vl + cur * 8192;

    // K fragments for this wave's 32-key half (shared across q-subtiles)
    bf16x8 kf[2][4];
#pragma unroll
    for (int ki = 0; ki < 2; ++ki) {
      int krow = ks * 32 + ki * 16 + lr;  // krow&15 == lr
#pragma unroll
      for (int dt = 0; dt < 4; ++dt)
        kf[ki][dt] = *(const bf16x8*)(Kb + krow * 128 + (((dt * 4 + lg) ^ lr) * 8));
    }

    // S^T = K @ Q^T : lane holds S[k=ks*32+ki*16+lg*4+r][q=q0+qh*16+lr]
    float sc[2][2][4];
#pragma unroll
    for (int qh = 0; qh < 2; ++qh)
#pragma unroll
      for (int ki = 0; ki < 2; ++ki) {
        f32x4 sa = {};
#pragma unroll
        for (int dt = 0; dt < 4; ++dt)
          sa = __builtin_amdgcn_mfma_f32_16x16x32_bf16(kf[ki][dt], qf[qh][dt], sa, 0, 0, 0);
#pragma unroll
        for (int r = 0; r < 4; ++r) {
          float s = sa[r] * SCALE;
          if (kb == qb) {
            int kg = kb * 64 + ks * 32 + ki * 16 + lg * 4 + r;
            if (kg > q0 + qh * 16 + lr) s = -1e30f;
          }
          sc[qh][ki][r] = s;
        }
      }

    // partial online softmax per q-subtile (q = lr), defer-max THR=8
    bf16x8 pf[2];
#pragma unroll
    for (int qh = 0; qh < 2; ++qh) {
      float t0 = fmaxf(fmaxf(sc[qh][0][0], sc[qh][0][1]), fmaxf(sc[qh][0][2], sc[qh][0][3]));
      float t1 = fmaxf(fmaxf(sc[qh][1][0], sc[qh][1][1]), fmaxf(sc[qh][1][2], sc[qh][1][3]));
      float tm = fmaxf(t0, t1);
      tm = fmaxf(tm, __shfl_xor(tm, 16));
      tm = fmaxf(tm, __shfl_xor(tm, 32));
      if (!__all(tm <= mm[qh] + 8.0f)) {
        float mn = fmaxf(mm[qh], tm);
        float al = __expf(mm[qh] - mn);
        mm[qh] = mn;
        lsum[qh] *= al;
        float a0 = __shfl(al, lg * 4 + 0);
        float a1 = __shfl(al, lg * 4 + 1);
        float a2 = __shfl(al, lg * 4 + 2);
        float a3 = __shfl(al, lg * 4 + 3);
#pragma unroll
        for (int dt = 0; dt < 8; ++dt) {
          oa[qh][dt][0] *= a0; oa[qh][dt][1] *= a1;
          oa[qh][dt][2] *= a2; oa[qh][dt][3] *= a3;
        }
      }
      float rs = 0.0f;
#pragma unroll
      for (int ki = 0; ki < 2; ++ki)
#pragma unroll
        for (int r = 0; r < 4; ++r) {
          float p = __expf(sc[qh][ki][r] - mm[qh]);
          sc[qh][ki][r] = p;
          rs += p;
        }
      rs += __shfl_xor(rs, 16);
      rs += __shfl_xor(rs, 32);
      lsum[qh] += rs;
      // pack P (32 keys -> one K=32 A-fragment): pf[qh][e] = sc[qh][e&1][e>>1]
      pf[qh][0] = (bf16_t)sc[qh][0][0]; pf[qh][1] = (bf16_t)sc[qh][1][0];
      pf[qh][2] = (bf16_t)sc[qh][0][1]; pf[qh][3] = (bf16_t)sc[qh][1][1];
      pf[qh][4] = (bf16_t)sc[qh][0][2]; pf[qh][5] = (bf16_t)sc[qh][1][2];
      pf[qh][6] = (bf16_t)sc[qh][0][3]; pf[qh][7] = (bf16_t)sc[qh][1][3];
    }

    // O += P @ V : V fragments (this k-half) shared across both q-subtiles
#pragma unroll
    for (int dt = 0; dt < 8; ++dt) {
      int R = dt * 8 + (lr >> 1);
      int slot = (((lr & 1) * 8 + ks * 4 + lg) ^ (R & 15));
      bf16x8 vf = *(const bf16x8*)(Vb + R * 128 + slot * 8);
      oa[0][dt] = __builtin_amdgcn_mfma_f32_16x16x32_bf16(pf[0], vf, oa[0][dt], 0, 0, 0);
      oa[1][dt] = __builtin_amdgcn_mfma_f32_16x16x32_bf16(pf[1], vf, oa[1][dt], 0, 0, 0);
    }

    asm volatile("s_waitcnt vmcnt(0)" ::: "memory");
    __syncthreads();
    cur ^= 1;
  }
#undef STAGE

  // ---- merge the two k-halves (ks=1 publishes, ks=0 combines & stores) ----
  float* Of = (float*)Kl;  // [qw][qh][dt][lane] f32x4 = 32KB
  float* Ms = (float*)Vl;  // m at [qw*32+qh*16+lr], l at +64
  if (ks == 1) {
#pragma unroll
    for (int qh = 0; qh < 2; ++qh)
#pragma unroll
      for (int dt = 0; dt < 8; ++dt)
        *(f32x4*)&Of[((((qw * 2 + qh) * 8) + dt) * 64 + l) * 4] = oa[qh][dt];
    if (lg == 0) {
#pragma unroll
      for (int qh = 0; qh < 2; ++qh) {
        Ms[qw * 32 + qh * 16 + lr] = mm[qh];
        Ms[64 + qw * 32 + qh * 16 + lr] = lsum[qh];
      }
    }
  }
  __syncthreads();
  if (ks == 0) {
#pragma unroll
    for (int qh = 0; qh < 2; ++qh) {
      float m1 = Ms[qw * 32 + qh * 16 + lr];
      float l1 = Ms[64 + qw * 32 + qh * 16 + lr];
      float msr = fmaxf(mm[qh], m1);
      float e0 = __expf(mm[qh] - msr), e1 = __expf(m1 - msr);
      float inv = 1.0f / (lsum[qh] * e0 + l1 * e1);
      float f0 = e0 * inv, f1 = e1 * inv;
      float f0r[4], f1r[4];
#pragma unroll
      for (int r = 0; r < 4; ++r) {
        f0r[r] = __shfl(f0, lg * 4 + r);
        f1r[r] = __shfl(f1, lg * 4 + r);
      }
#pragma unroll
      for (int dt = 0; dt < 8; ++dt) {
        f32x4 o1 = *(const f32x4*)&Of[((((qw * 2 + qh) * 8) + dt) * 64 + l) * 4];
        int d = h * HDIM + dt * 16 + lr;
#pragma unroll
        for (int r = 0; r < 4; ++r) {
          float v = oa[qh][dt][r] * f0r[r] + o1[r] * f1r[r];
          AO[(size_t)(q0 + qh * 16 + lg * 4 + r) * HID + d] = (bf16_t)v;
        }
      }
    }
  }
}

extern "C" void kernel_launch(void* const* d_in, const int* in_sizes, int n_in,
                              void* d_out, int out_size, void* d_ws, size_t ws_size,
                              hipStream_t stream) {
  (void)in_sizes; (void)n_in; (void)out_size; (void)ws_size;
  const float* x  = (const float*)d_in[0];
  const float* Wq = (const float*)d_in[1];
  const float* bq = (const float*)d_in[2];
  const float* Wk = (const float*)d_in[3];
  const float* bk = (const float*)d_in[4];
  const float* Wv = (const float*)d_in[5];
  const float* bv = (const float*)d_in[6];
  const float* Wo = (const float*)d_in[7];
  float* outp = (float*)d_out;

  char* ws = (char*)d_ws;
  const size_t OFF_XB   = 0;                      // [2048][2048] bf16
  const size_t OFF_WQKV = 8388608;                // [2560][2048] bf16 (Wq^T;Wk^T;Wv^T)
  const size_t OFF_WOT  = OFF_WQKV + 10485760;    // [2048][2048] bf16
  const size_t OFF_QKV  = OFF_WOT + 8388608;      // [2048][2560] bf16 (V cols unused)
  const size_t OFF_VT   = OFF_QKV + 10485760;     // [256][2048] bf16 (sigma-interleaved)
  const size_t OFF_AO   = OFF_VT + 1048576;       // [2048][2048] bf16
  const size_t OFF_BIAS = OFF_AO + 8388608;       // [2560] fp32
  bf16_t* xb    = (bf16_t*)(ws + OFF_XB);
  bf16_t* WqkvT = (bf16_t*)(ws + OFF_WQKV);
  bf16_t* WoT   = (bf16_t*)(ws + OFF_WOT);
  bf16_t* QKV   = (bf16_t*)(ws + OFF_QKV);
  bf16_t* Vg    = (bf16_t*)(ws + OFF_VT);
  bf16_t* AO    = (bf16_t*)(ws + OFF_AO);
  float*  bias  = (float*)(ws + OFF_BIAS);

  k_prep<<<4362, 256, 0, stream>>>(x, Wq, Wk, Wv, Wo, bq, bk, bv, xb, WqkvT, WoT, bias);
  k_proj<<<256, 256, 0, stream>>>(xb, WqkvT, bias, QKV, Vg);
  k_attn<<<dim3(16, 32), 256, 0, stream>>>(QKV, Vg, AO);
  k_gemm<0, float><<<dim3(16, 16), 256, 0, stream>>>(AO, WoT, nullptr, outp, 2048, 2048, 2048);
}